// Round 9
// baseline (271.357 us; speedup 1.0000x reference)
//
#include <hip/hip_runtime.h>

// SymplecticLayer: 2 leapfrog steps; force = grad of tanh-MLP Hamiltonian (8->128->128->1).
// v10: v9 persistent structure + W2B B-fragments hoisted into REGISTERS.
//   - pipe model (v3/v9 counters): LDS pipe is binding (~50 KB/wave-eval -> ~167us floor
//     incl conflicts) vs trans ~123us. 32 of 38 b128-reads/eval are W2B/W2T B-frag
//     re-reads of IDENTICAL per-lane addresses every eval.
//   - fix: read the 8 W2B fragments (8 x i32x8 = 64 VGPR) ONCE per wave after the staging
//     barrier; reuse across 8 jobs x 4 evals. Statically indexed (full unroll) -> registers.
//     Cuts 16 KB + 16 read-issues per wave-eval; LDS floor ~167 -> ~121us.
//   - VGPR 52 -> ~120 (<=128 keeps 4 waves/SIMD; 16 waves/CU unchanged). W2T stays in LDS
//     (hoisting it too would cost occupancy: 180 regs -> 2 waves/SIMD).
//   - schedule: grid=512 x 8 waves = 4096 slots, 32768 jobs = exactly 8 jobs/wave;
//     single dispatch, no atomics, no prep kernel.
//   - math identical to v6..v9 (verified): K=128 mfma_scale f8f6f4 (unit scales), tr8
//     transpose reads, multiplicative bias folds, W3 folded into W2T, d2 = rr - rr^2.

typedef float f32x2 __attribute__((ext_vector_type(2)));
typedef float f32x4 __attribute__((ext_vector_type(4)));
typedef int   i32x2 __attribute__((ext_vector_type(2)));
typedef int   i32x4 __attribute__((ext_vector_type(4)));
typedef int   i32x8 __attribute__((ext_vector_type(8)));

#define DT 0.01f
#define S1 64.0f              // d1 scale (fp8 dynamic-range placement)
#define TWO_LOG2E 2.8853900817779268f
#define SCL1 0x7F7F7F7F       // e8m0 1.0 in all four bytes

// LDS fragment layout (fp8 bytes). K=128 regions use the byte map:
//   register byte p (0..31) of quad qd  <->  k = 32*(p>>3) + 8*qd + (p&7)
// identical on A and B sides, so any internal HW k-permutation cancels.
#define OFF_W1B 0             // 1024 : L1 fwd B-frags (k=0..7 only), scaled 2log2e
#define OFF_W2B 1024          // 16384: L2 fwd B-frags, K=128, scaled 2log2e
#define OFF_W2T 17408         // 16384: L2 bwd B-frags, K=128, scaled 256*w3
#define OFF_W1T 33792         // 1024 : L1 bwd B-frags, K=128, n=0..7 compact
#define WTOT    34816

__device__ __forceinline__ unsigned char to_fp8(float x) {
    return (unsigned char)(__builtin_amdgcn_cvt_pk_fp8_f32(x, x, 0, false) & 0xff);
}
__device__ __forceinline__ float fexp2(float x) {
#if __has_builtin(__builtin_amdgcn_exp2f)
    return __builtin_amdgcn_exp2f(x);
#else
    return exp2f(x);
#endif
}
__device__ __forceinline__ float frcp(float x) {
#if __has_builtin(__builtin_amdgcn_rcpf)
    return __builtin_amdgcn_rcpf(x);
#else
    return 1.0f / x;
#endif
}

// hardware transpose read: lane gathers 8 bytes at stride 16 from its own address
__device__ __forceinline__ i32x2 tr8(unsigned char* p) {
#if __has_builtin(__builtin_amdgcn_ds_read_tr8_b64)
    return __builtin_amdgcn_ds_read_tr8_b64((__attribute__((address_space(3))) i32x2*)p);
#else
    i32x2 d;
    asm volatile("ds_read_b64_tr_b8 %0, %1\n\ts_waitcnt lgkmcnt(0)"
                 : "=v"(d)
                 : "v"((unsigned)(unsigned long long)(__attribute__((address_space(3))) void*)p)
                 : "memory");
    __builtin_amdgcn_sched_barrier(0);
    return d;
#endif
}

__device__ __forceinline__ i32x8 cat44(i32x4 a, i32x4 b) {
    return __builtin_shufflevector(a, b, 0, 1, 2, 3, 4, 5, 6, 7);
}

// A-fragment for K=128: 4 transposed b64 reads, chunk c at +c*512 (32 cols * 16B)
__device__ __forceinline__ i32x8 read_a(unsigned char* abase) {
    i32x2 a0 = tr8(abase);
    i32x2 a1 = tr8(abase + 512);
    i32x2 a2 = tr8(abase + 1024);
    i32x2 a3 = tr8(abase + 1536);
    i32x4 lo = __builtin_shufflevector(a0, a1, 0, 1, 2, 3);
    i32x4 hi = __builtin_shufflevector(a2, a3, 0, 1, 2, 3);
    return cat44(lo, hi);
}

// K=128 fp8 matmul-accumulate, unit block scales; fallback = 4 x K=32 (same byte map)
__device__ __forceinline__ f32x4 mm128(i32x8 a, i32x8 b, f32x4 c) {
#if __has_builtin(__builtin_amdgcn_mfma_scale_f32_16x16x128_f8f6f4)
    return __builtin_amdgcn_mfma_scale_f32_16x16x128_f8f6f4(a, b, c, 0, 0, 0, SCL1, 0, SCL1);
#else
    #pragma unroll
    for (int kt = 0; kt < 4; kt++) {
        long long aa = ((long long)(unsigned)a[2 * kt + 1] << 32) | (unsigned)a[2 * kt];
        long long bb = ((long long)(unsigned)b[2 * kt + 1] << 32) | (unsigned)b[2 * kt];
        c = __builtin_amdgcn_mfma_f32_16x16x32_fp8_fp8(aa, bb, c, 0, 0, 0);
    }
    return c;
#endif
}

#define NWAVES 8
#define BLOCKT (64 * NWAVES)

// ---------------- persistent fused leapfrog ----------------
__global__ __launch_bounds__(BLOCKT) void hnn_leapfrog_kernel(
    const float* __restrict__ Z, const float* __restrict__ W1,
    const float* __restrict__ B1f, const float* __restrict__ W2,
    const float* __restrict__ B2f, const float* __restrict__ W3,
    float* __restrict__ OUT, int njobs)
{
    __shared__ __align__(16) unsigned char sWT[WTOT];            // weight fragments
    __shared__ __align__(16) unsigned char sACT[NWAVES * 2048];  // per-wave act tile
    __shared__ __align__(16) float sZ[NWAVES * 128];

    const int t = threadIdx.x;

    // ---- one-time per-block weight swizzle (amortized over 8 jobs x 8 waves) ----
    for (int i = t; i < 1024; i += BLOCKT) {
        int row = i >> 7, col = i & 127;              // W1[row][col]: row = dim k (0..7)
        float w = W1[i];
        // fwd compact (k=0..7 only): byte = nt*128 + nn*8 + k
        sWT[OFF_W1B + (col >> 4) * 128 + (col & 15) * 8 + row] = to_fp8(w * TWO_LOG2E);
        // bwd compact (n=0..7): k-dim = col; [h][qd][n][s]
        int c = col >> 5, h = c >> 1, s = (c & 1) * 8 + (col & 7);
        int qd2 = (col >> 3) & 3;
        sWT[OFF_W1T + ((h * 4 + qd2) * 8 + row) * 16 + s] = to_fp8(w);
    }
    for (int i = t; i < 4096; i += BLOCKT) {
        f32x4 w = ((const f32x4*)W2)[i];
        int base = i * 4;
        int row = base >> 7, col0 = base & 127;       // W2[row][col0..col0+3]
        int cR = row >> 5, hR = cR >> 1, sR = (cR & 1) * 8 + (row & 7);
        int qR = (row >> 3) & 3;
        #pragma unroll
        for (int u = 0; u < 4; u++) {
            int col = col0 + u;
            // fwd: k-dim = row (h1 index), n = col (h2 index)
            sWT[OFF_W2B + (((col >> 4) * 2 + hR) * 64 + qR * 16 + (col & 15)) * 16 + sR] =
                to_fp8(w[u] * TWO_LOG2E);
            // bwd: k-dim = col, n = row; fold 256*w3[col]
            int cC = col >> 5, hC = cC >> 1, sC = (cC & 1) * 8 + (col & 7);
            int qC = (col >> 3) & 3;
            sWT[OFF_W2T + (((row >> 4) * 2 + hC) * 64 + qC * 16 + (row & 15)) * 16 + sC] =
                to_fp8(w[u] * 256.0f * W3[col]);
        }
    }

    const int lane = t & 63;
    const int wv   = t >> 6;
    const int nn   = lane & 15;
    const int qd   = lane >> 4;

    // multiplicative bias folds: e^(y+b) = exp2(c) * eb  (exact f32, no fp8 bias quant)
    float eb1v[8], eb2v[8];
    #pragma unroll
    for (int nt = 0; nt < 8; nt++) {
        eb1v[nt] = fexp2(B1f[nt * 16 + nn] * TWO_LOG2E);
        eb2v[nt] = fexp2(B2f[nt * 16 + nn] * TWO_LOG2E);
    }
    __syncthreads();
    // no further block barriers: each wave works on private LDS slices

    unsigned char* act   = sACT + wv * 2048;
    float*         zrow  = sZ + wv * 128;                   // wave's 16 rows x 8 floats
    unsigned char* abase = act + qd * 128 + nn;             // tr8 read base
    unsigned char* awr   = act + nn * 16 + qd * 4;          // packed C-store base (+nt*256)
    const unsigned char* w1b  = sWT + OFF_W1B + nn * 8;     // broadcast across qd
    const unsigned char* w16  = sWT + lane * 16;            // K=128 B-frag base (W2T)
    const unsigned char* w1t  = sWT + OFF_W1T + (qd * 8 + (nn & 7)) * 16;

    // ---- hoist W2B fragments into registers: read ONCE, reuse 8 jobs x 4 evals ----
    i32x8 b2r[8];
    #pragma unroll
    for (int nt = 0; nt < 8; nt++) {
        i32x4 bA = *(const i32x4*)(w16 + OFF_W2B + nt * 2048);
        i32x4 bB = *(const i32x4*)(w16 + OFF_W2B + nt * 2048 + 1024);
        b2r[nt] = cat44(bA, bB);
    }

    const f32x4 zc = {0.f, 0.f, 0.f, 0.f};

    // ---- static schedule: grid*NWAVES slots divide njobs exactly (8 jobs/wave) ----
    const int stride = gridDim.x * NWAVES;
    int job = blockIdx.x * NWAVES + wv;
    int jcl = job < njobs ? job : 0;
    f32x2 zv = ((const f32x2*)(Z + jcl * 128))[lane];

    #pragma unroll 1
    while (job < njobs) {
        int nxt = job + stride;
        int ncl = nxt < njobs ? nxt : 0;
        f32x2 zn = ((const f32x2*)(Z + ncl * 128))[lane];   // prefetch next z

        ((f32x2*)zrow)[lane] = zv;                          // stage current z tile

        #pragma unroll 1
        for (int ev = 0; ev < 4; ev++) {
            // ================= L1 forward: h1 = tanh(z @ W1 + b1) =================
            long long az = 0;
            if (qd == 0) {
                const f32x4* zr = (const f32x4*)(zrow + nn * 8);
                f32x4 z0 = zr[0], z1 = zr[1];
                int lo = __builtin_amdgcn_cvt_pk_fp8_f32(z0[0], z0[1], 0, false);
                lo     = __builtin_amdgcn_cvt_pk_fp8_f32(z0[2], z0[3], lo, true);
                int hi = __builtin_amdgcn_cvt_pk_fp8_f32(z1[0], z1[1], 0, false);
                hi     = __builtin_amdgcn_cvt_pk_fp8_f32(z1[2], z1[3], hi, true);
                az = ((long long)(unsigned)hi << 32) | (unsigned)lo;
            }
            float hc[8][4];                                 // h1 kept for backward factor
            #pragma unroll
            for (int nt = 0; nt < 8; nt++) {
                // all lanes read same 8B (broadcast); qd>0 lanes' A bytes are 0
                long long bf = *(const long long*)(w1b + nt * 128);
                f32x4 c = __builtin_amdgcn_mfma_f32_16x16x32_fp8_fp8(az, bf, zc, 0, 0, 0);
                #pragma unroll
                for (int r = 0; r < 4; r++) {
                    float e  = fexp2(c[r]);                 // input already *2log2e
                    float rr = frcp(fmaf(e, eb1v[nt], 1.0f));
                    hc[nt][r] = fmaf(-2.0f, rr, 1.0f);      // tanh
                }
                int v = __builtin_amdgcn_cvt_pk_fp8_f32(hc[nt][0], hc[nt][1], 0, false);
                v     = __builtin_amdgcn_cvt_pk_fp8_f32(hc[nt][2], hc[nt][3], v, true);
                *(int*)(awr + nt * 256) = v;                // conflict-free b32 store
            }
            // ================= L2 forward: store sech^2/4 = rr - rr^2 =================
            i32x8 a8 = read_a(abase);
            #pragma unroll
            for (int nt = 0; nt < 8; nt++) {
                f32x4 c = mm128(a8, b2r[nt], zc);           // B from registers (hoisted)
                float dd[4];
                #pragma unroll
                for (int r = 0; r < 4; r++) {
                    float e  = fexp2(c[r]);
                    float rr = frcp(fmaf(e, eb2v[nt], 1.0f));
                    dd[r] = fmaf(-rr, rr, rr);              // rr - rr^2 (w3 in W2T)
                }
                int v = __builtin_amdgcn_cvt_pk_fp8_f32(dd[0], dd[1], 0, false);
                v     = __builtin_amdgcn_cvt_pk_fp8_f32(dd[2], dd[3], v, true);
                *(int*)(awr + nt * 256) = v;                // overwrite h1 (consumed)
            }
            // ================= L2 backward: d1 = (1-h1^2)*(a @ 256*w3*W2^T) =========
            a8 = read_a(abase);
            #pragma unroll
            for (int nt = 0; nt < 8; nt++) {
                i32x4 bA = *(const i32x4*)(w16 + OFF_W2T + nt * 2048);
                i32x4 bB = *(const i32x4*)(w16 + OFF_W2T + nt * 2048 + 1024);
                f32x4 c = mm128(a8, cat44(bA, bB), zc);
                float dd[4];
                #pragma unroll
                for (int r = 0; r < 4; r++) {
                    float h = hc[nt][r];
                    dd[r] = c[r] * fmaf(-h, h, 1.0f);       // carries S1=64 scale
                }
                int v = __builtin_amdgcn_cvt_pk_fp8_f32(dd[0], dd[1], 0, false);
                v     = __builtin_amdgcn_cvt_pk_fp8_f32(dd[2], dd[3], v, true);
                *(int*)(awr + nt * 256) = v;
            }
            // ================= L1 backward: g = d1 @ W1^T (cols 0..7 valid) =========
            a8 = read_a(abase);
            i32x4 bA = *(const i32x4*)(w1t);                // nn>=8 lanes read dup cols
            i32x4 bB = *(const i32x4*)(w1t + 512);
            f32x4 g = mm128(a8, cat44(bA, bB), zc);
            // ============ symplectic update (C-layout: col nn, rows qd*4+r) =========
            const bool first = (ev & 1) == 0;
            if (nn < 4) {
                float* p = zrow + qd * 32 + nn + 4;         // dHdq -> p -= 0.5*DT*g
                #pragma unroll
                for (int r = 0; r < 4; r++) p[r * 8] -= (0.5f * DT / S1) * g[r];
            } else if (nn < 8 && first) {
                float* p = zrow + qd * 32 + (nn - 4);       // dHdp -> q += DT*g
                #pragma unroll
                for (int r = 0; r < 4; r++) p[r * 8] += (DT / S1) * g[r];
            }
        }

        // ---- write back (coalesced per wave) ----
        OUT[job * 128 + lane]      = zrow[lane];
        OUT[job * 128 + 64 + lane] = zrow[64 + lane];

        job = nxt;
        zv  = zn;
    }
}

extern "C" void kernel_launch(void* const* d_in, const int* in_sizes, int n_in,
                              void* d_out, int out_size, void* d_ws, size_t ws_size,
                              hipStream_t stream) {
    const float* Z  = (const float*)d_in[0];
    const float* W1 = (const float*)d_in[1];
    const float* B1 = (const float*)d_in[2];
    const float* W2 = (const float*)d_in[3];
    const float* B2 = (const float*)d_in[4];
    const float* W3 = (const float*)d_in[5];
    float* OUT = (float*)d_out;
    int njobs = in_sizes[0] / 128;                  // 16 batch rows per wave-job
    int grid  = 512;                                // 4096 slots = njobs/8 (exact)
    int maxg  = (njobs + NWAVES - 1) / NWAVES;
    if (grid > maxg) grid = maxg;
    hipLaunchKernelGGL(hnn_leapfrog_kernel, dim3(grid), dim3(BLOCKT), 0, stream,
                       Z, W1, B1, W2, B2, W3, OUT, njobs);
}

// Round 10
// 251.842 us; speedup vs baseline: 1.0775x; 1.0775x over previous
//
#include <hip/hip_runtime.h>

// SymplecticLayer: 2 leapfrog steps; force = grad of tanh-MLP Hamiltonian (8->128->128->1).
// v11: prep-kernel staging + persistent exact-balance main (best pieces of v3 and v9).
//   - v10 post-mortem: hoisting B-frags to registers put them in AGPRs (unified file);
//     total regs ~148 -> 3 waves/SIMD -> occupancy 22.6% -> regression. Reverted.
//   - v9 vs v3 gap (213 vs 195) = in-kernel swizzle's scatter-byte-store bank conflicts
//     (1.53e7 vs 9.4e6) + swizzle VALU. Fix: prep kernel swizzles fp8 frags to d_ws ONCE
//     (65 blocks); main stages 34816 B via conflict-free global_load_lds, 512 stagings
//     total (v3 did 4096 -> ~10% of each block's lifetime; now /8).
//   - schedule: grid=512 x 8 waves = 4096 slots, 32768 jobs = exactly 8 jobs/wave.
//     No tail, no imbalance, no atomics. LDS 55296 -> 2 blocks/CU (16 waves, v3-proven).
//   - NOTE: VALUBusy+MfmaUtil ~= 99% at v3 -> SIMD issue near-saturated; more waves
//     won't pay, fewer instructions or less staging is the lever (this round: staging).
//   - math identical to v6..v10 (verified): K=128 mfma_scale f8f6f4 (unit scales), tr8
//     transpose reads, multiplicative bias folds, W3 folded into W2T, d2 = rr - rr^2.

typedef float f32x2 __attribute__((ext_vector_type(2)));
typedef float f32x4 __attribute__((ext_vector_type(4)));
typedef int   i32x2 __attribute__((ext_vector_type(2)));
typedef int   i32x4 __attribute__((ext_vector_type(4)));
typedef int   i32x8 __attribute__((ext_vector_type(8)));

#define DT 0.01f
#define S1 64.0f              // d1 scale (fp8 dynamic-range placement)
#define TWO_LOG2E 2.8853900817779268f
#define SCL1 0x7F7F7F7F       // e8m0 1.0 in all four bytes

// workspace / LDS fragment layout (fp8 bytes). K=128 regions use the byte map:
//   register byte p (0..31) of quad qd  <->  k = 32*(p>>3) + 8*qd + (p&7)
// identical on A and B sides, so any internal HW k-permutation cancels.
#define OFF_W1B 0             // 1024 : L1 fwd B-frags (k=0..7 only), scaled 2log2e
#define OFF_W2B 1024          // 16384: L2 fwd B-frags, K=128, scaled 2log2e
#define OFF_W2T 17408         // 16384: L2 bwd B-frags, K=128, scaled 256*w3
#define OFF_W1T 33792         // 1024 : L1 bwd B-frags, K=128, n=0..7 compact
#define WTOT    34816

__device__ __forceinline__ unsigned char to_fp8(float x) {
    return (unsigned char)(__builtin_amdgcn_cvt_pk_fp8_f32(x, x, 0, false) & 0xff);
}
__device__ __forceinline__ float fexp2(float x) {
#if __has_builtin(__builtin_amdgcn_exp2f)
    return __builtin_amdgcn_exp2f(x);
#else
    return exp2f(x);
#endif
}
__device__ __forceinline__ float frcp(float x) {
#if __has_builtin(__builtin_amdgcn_rcpf)
    return __builtin_amdgcn_rcpf(x);
#else
    return 1.0f / x;
#endif
}

// hardware transpose read: lane gathers 8 bytes at stride 16 from its own address
__device__ __forceinline__ i32x2 tr8(unsigned char* p) {
#if __has_builtin(__builtin_amdgcn_ds_read_tr8_b64)
    return __builtin_amdgcn_ds_read_tr8_b64((__attribute__((address_space(3))) i32x2*)p);
#else
    i32x2 d;
    asm volatile("ds_read_b64_tr_b8 %0, %1\n\ts_waitcnt lgkmcnt(0)"
                 : "=v"(d)
                 : "v"((unsigned)(unsigned long long)(__attribute__((address_space(3))) void*)p)
                 : "memory");
    __builtin_amdgcn_sched_barrier(0);
    return d;
#endif
}

__device__ __forceinline__ i32x8 cat44(i32x4 a, i32x4 b) {
    return __builtin_shufflevector(a, b, 0, 1, 2, 3, 4, 5, 6, 7);
}

// A-fragment for K=128: 4 transposed b64 reads, chunk c at +c*512 (32 cols * 16B)
__device__ __forceinline__ i32x8 read_a(unsigned char* abase) {
    i32x2 a0 = tr8(abase);
    i32x2 a1 = tr8(abase + 512);
    i32x2 a2 = tr8(abase + 1024);
    i32x2 a3 = tr8(abase + 1536);
    i32x4 lo = __builtin_shufflevector(a0, a1, 0, 1, 2, 3);
    i32x4 hi = __builtin_shufflevector(a2, a3, 0, 1, 2, 3);
    return cat44(lo, hi);
}

// K=128 fp8 matmul-accumulate, unit block scales; fallback = 4 x K=32 (same byte map)
__device__ __forceinline__ f32x4 mm128(i32x8 a, i32x8 b, f32x4 c) {
#if __has_builtin(__builtin_amdgcn_mfma_scale_f32_16x16x128_f8f6f4)
    return __builtin_amdgcn_mfma_scale_f32_16x16x128_f8f6f4(a, b, c, 0, 0, 0, SCL1, 0, SCL1);
#else
    #pragma unroll
    for (int kt = 0; kt < 4; kt++) {
        long long aa = ((long long)(unsigned)a[2 * kt + 1] << 32) | (unsigned)a[2 * kt];
        long long bb = ((long long)(unsigned)b[2 * kt + 1] << 32) | (unsigned)b[2 * kt];
        c = __builtin_amdgcn_mfma_f32_16x16x32_fp8_fp8(aa, bb, c, 0, 0, 0);
    }
    return c;
#endif
}

// ---------------- prep: swizzle fp8 weight fragments into workspace ----------------
__global__ __launch_bounds__(256) void hnn_prep_kernel(
    const float* __restrict__ W1, const float* __restrict__ W2,
    const float* __restrict__ W3, unsigned char* __restrict__ ws)
{
    const int t = threadIdx.x, b = blockIdx.x;
    if (b == 0) {
        for (int i = t; i < 1024; i += 256) {
            int row = i >> 7, col = i & 127;          // W1[row][col]: row = dim k (0..7)
            float w = W1[i];
            // fwd compact (k=0..7 only): byte = nt*128 + nn*8 + k
            ws[OFF_W1B + (col >> 4) * 128 + (col & 15) * 8 + row] = to_fp8(w * TWO_LOG2E);
            // bwd compact (n=0..7): k-dim = col; [h][qd][n][s], h = col>>6
            int c = col >> 5, h = c >> 1, s = (c & 1) * 8 + (col & 7);
            int qd2 = (col >> 3) & 3;
            ws[OFF_W1T + ((h * 4 + qd2) * 8 + row) * 16 + s] = to_fp8(w);
        }
    } else {
        int idx = (b - 1) * 256 + t;                  // 0..16383
        int row = idx >> 7, col = idx & 127;          // W2[row][col]
        float w = W2[idx];
        {   // fwd: k-dim = row (h1 index), n = col (h2 index)
            int c = row >> 5, h = c >> 1, s = (c & 1) * 8 + (row & 7);
            int qd2 = (row >> 3) & 3;
            ws[OFF_W2B + (((col >> 4) * 2 + h) * 64 + qd2 * 16 + (col & 15)) * 16 + s] =
                to_fp8(w * TWO_LOG2E);
        }
        {   // bwd: k-dim = col, n = row; fold 256*w3[col] (A-frag carries sech^2/4)
            int c = col >> 5, h = c >> 1, s = (c & 1) * 8 + (col & 7);
            int qd2 = (col >> 3) & 3;
            ws[OFF_W2T + (((row >> 4) * 2 + h) * 64 + qd2 * 16 + (row & 15)) * 16 + s] =
                to_fp8(w * 256.0f * W3[col]);
        }
    }
}

#define NWAVES 8
#define BLOCKT (64 * NWAVES)

// ---------------- persistent fused leapfrog ----------------
__global__ __launch_bounds__(BLOCKT) void hnn_leapfrog_kernel(
    const float* __restrict__ Z, const unsigned char* __restrict__ WS,
    const float* __restrict__ B1f, const float* __restrict__ B2f,
    float* __restrict__ OUT, int njobs)
{
    __shared__ __align__(16) unsigned char sWT[WTOT];            // weight fragments
    __shared__ __align__(16) unsigned char sACT[NWAVES * 2048];  // per-wave act tile
    __shared__ __align__(16) float sZ[NWAVES * 128];

    const int t = threadIdx.x;

    // ---- stage weight fragments via conflict-free global_load_lds (once per block) ----
    for (int i = t; i < WTOT / 16; i += BLOCKT)
        __builtin_amdgcn_global_load_lds(
            (const __attribute__((address_space(1))) void*)(WS + i * 16),
            (__attribute__((address_space(3))) void*)(sWT + i * 16), 16, 0, 0);

    const int lane = t & 63;
    const int wv   = t >> 6;
    const int nn   = lane & 15;
    const int qd   = lane >> 4;

    // multiplicative bias folds: e^(y+b) = exp2(c) * eb  (exact f32, no fp8 bias quant)
    float eb1v[8], eb2v[8];
    #pragma unroll
    for (int nt = 0; nt < 8; nt++) {
        eb1v[nt] = fexp2(B1f[nt * 16 + nn] * TWO_LOG2E);
        eb2v[nt] = fexp2(B2f[nt * 16 + nn] * TWO_LOG2E);
    }
    __syncthreads();
    // no further block barriers: each wave works on private LDS slices

    unsigned char* act   = sACT + wv * 2048;
    float*         zrow  = sZ + wv * 128;                   // wave's 16 rows x 8 floats
    unsigned char* abase = act + qd * 128 + nn;             // tr8 read base
    unsigned char* awr   = act + nn * 16 + qd * 4;          // packed C-store base (+nt*256)
    const unsigned char* w1b  = sWT + OFF_W1B + nn * 8;     // broadcast across qd
    const unsigned char* w16  = sWT + lane * 16;            // K=128 B-frag base (W2B/W2T)
    const unsigned char* w1t  = sWT + OFF_W1T + (qd * 8 + (nn & 7)) * 16;

    const f32x4 zc = {0.f, 0.f, 0.f, 0.f};

    // ---- static schedule: grid*NWAVES slots divide njobs exactly (8 jobs/wave) ----
    const int stride = gridDim.x * NWAVES;
    int job = blockIdx.x * NWAVES + wv;
    int jcl = job < njobs ? job : 0;
    f32x2 zv = ((const f32x2*)(Z + jcl * 128))[lane];

    #pragma unroll 1
    while (job < njobs) {
        int nxt = job + stride;
        int ncl = nxt < njobs ? nxt : 0;
        f32x2 zn = ((const f32x2*)(Z + ncl * 128))[lane];   // prefetch next z

        ((f32x2*)zrow)[lane] = zv;                          // stage current z tile

        #pragma unroll 1
        for (int ev = 0; ev < 4; ev++) {
            // ================= L1 forward: h1 = tanh(z @ W1 + b1) =================
            long long az = 0;
            if (qd == 0) {
                const f32x4* zr = (const f32x4*)(zrow + nn * 8);
                f32x4 z0 = zr[0], z1 = zr[1];
                int lo = __builtin_amdgcn_cvt_pk_fp8_f32(z0[0], z0[1], 0, false);
                lo     = __builtin_amdgcn_cvt_pk_fp8_f32(z0[2], z0[3], lo, true);
                int hi = __builtin_amdgcn_cvt_pk_fp8_f32(z1[0], z1[1], 0, false);
                hi     = __builtin_amdgcn_cvt_pk_fp8_f32(z1[2], z1[3], hi, true);
                az = ((long long)(unsigned)hi << 32) | (unsigned)lo;
            }
            float hc[8][4];                                 // h1 kept for backward factor
            #pragma unroll
            for (int nt = 0; nt < 8; nt++) {
                // all lanes read same 8B (broadcast); qd>0 lanes' A bytes are 0
                long long bf = *(const long long*)(w1b + nt * 128);
                f32x4 c = __builtin_amdgcn_mfma_f32_16x16x32_fp8_fp8(az, bf, zc, 0, 0, 0);
                #pragma unroll
                for (int r = 0; r < 4; r++) {
                    float e  = fexp2(c[r]);                 // input already *2log2e
                    float rr = frcp(fmaf(e, eb1v[nt], 1.0f));
                    hc[nt][r] = fmaf(-2.0f, rr, 1.0f);      // tanh
                }
                int v = __builtin_amdgcn_cvt_pk_fp8_f32(hc[nt][0], hc[nt][1], 0, false);
                v     = __builtin_amdgcn_cvt_pk_fp8_f32(hc[nt][2], hc[nt][3], v, true);
                *(int*)(awr + nt * 256) = v;                // conflict-free b32 store
            }
            // ================= L2 forward: store sech^2/4 = rr - rr^2 =================
            i32x8 a8 = read_a(abase);
            #pragma unroll
            for (int nt = 0; nt < 8; nt++) {
                i32x4 bA = *(const i32x4*)(w16 + OFF_W2B + nt * 2048);
                i32x4 bB = *(const i32x4*)(w16 + OFF_W2B + nt * 2048 + 1024);
                f32x4 c = mm128(a8, cat44(bA, bB), zc);
                float dd[4];
                #pragma unroll
                for (int r = 0; r < 4; r++) {
                    float e  = fexp2(c[r]);
                    float rr = frcp(fmaf(e, eb2v[nt], 1.0f));
                    dd[r] = fmaf(-rr, rr, rr);              // rr - rr^2 (w3 in W2T)
                }
                int v = __builtin_amdgcn_cvt_pk_fp8_f32(dd[0], dd[1], 0, false);
                v     = __builtin_amdgcn_cvt_pk_fp8_f32(dd[2], dd[3], v, true);
                *(int*)(awr + nt * 256) = v;                // overwrite h1 (consumed)
            }
            // ================= L2 backward: d1 = (1-h1^2)*(a @ 256*w3*W2^T) =========
            a8 = read_a(abase);
            #pragma unroll
            for (int nt = 0; nt < 8; nt++) {
                i32x4 bA = *(const i32x4*)(w16 + OFF_W2T + nt * 2048);
                i32x4 bB = *(const i32x4*)(w16 + OFF_W2T + nt * 2048 + 1024);
                f32x4 c = mm128(a8, cat44(bA, bB), zc);
                float dd[4];
                #pragma unroll
                for (int r = 0; r < 4; r++) {
                    float h = hc[nt][r];
                    dd[r] = c[r] * fmaf(-h, h, 1.0f);       // carries S1=64 scale
                }
                int v = __builtin_amdgcn_cvt_pk_fp8_f32(dd[0], dd[1], 0, false);
                v     = __builtin_amdgcn_cvt_pk_fp8_f32(dd[2], dd[3], v, true);
                *(int*)(awr + nt * 256) = v;
            }
            // ================= L1 backward: g = d1 @ W1^T (cols 0..7 valid) =========
            a8 = read_a(abase);
            i32x4 bA = *(const i32x4*)(w1t);                // nn>=8 lanes read dup cols
            i32x4 bB = *(const i32x4*)(w1t + 512);
            f32x4 g = mm128(a8, cat44(bA, bB), zc);
            // ============ symplectic update (C-layout: col nn, rows qd*4+r) =========
            const bool first = (ev & 1) == 0;
            if (nn < 4) {
                float* p = zrow + qd * 32 + nn + 4;         // dHdq -> p -= 0.5*DT*g
                #pragma unroll
                for (int r = 0; r < 4; r++) p[r * 8] -= (0.5f * DT / S1) * g[r];
            } else if (nn < 8 && first) {
                float* p = zrow + qd * 32 + (nn - 4);       // dHdp -> q += DT*g
                #pragma unroll
                for (int r = 0; r < 4; r++) p[r * 8] += (DT / S1) * g[r];
            }
        }

        // ---- write back (coalesced per wave) ----
        OUT[job * 128 + lane]      = zrow[lane];
        OUT[job * 128 + 64 + lane] = zrow[64 + lane];

        job = nxt;
        zv  = zn;
    }
}

extern "C" void kernel_launch(void* const* d_in, const int* in_sizes, int n_in,
                              void* d_out, int out_size, void* d_ws, size_t ws_size,
                              hipStream_t stream) {
    const float* Z  = (const float*)d_in[0];
    const float* W1 = (const float*)d_in[1];
    const float* B1 = (const float*)d_in[2];
    const float* W2 = (const float*)d_in[3];
    const float* B2 = (const float*)d_in[4];
    const float* W3 = (const float*)d_in[5];
    float* OUT = (float*)d_out;
    unsigned char* ws = (unsigned char*)d_ws;
    int njobs = in_sizes[0] / 128;                  // 16 batch rows per wave-job
    int grid  = 512;                                // 4096 slots = njobs/8 (exact)
    int maxg  = (njobs + NWAVES - 1) / NWAVES;
    if (grid > maxg) grid = maxg;
    hipLaunchKernelGGL(hnn_prep_kernel, dim3(65), dim3(256), 0, stream, W1, W2, W3, ws);
    hipLaunchKernelGGL(hnn_leapfrog_kernel, dim3(grid), dim3(BLOCKT), 0, stream,
                       Z, ws, B1, B2, OUT, njobs);
}